// Round 7
// baseline (893.358 us; speedup 1.0000x reference)
//
#include <hip/hip_runtime.h>
#include <math.h>

#define N_NODES 100000
#define N_EDGES 3200000
#define N_TOT   (N_EDGES + N_NODES)
#define F_IN    512
#define HID     16
#define NCLS    32
#define NEG_SLOPE 0.2f

#define BSH   7                       // bucket shift: 128 nodes per bucket
#define NBKT  ((N_NODES + 127) / 128) // 782
#define SRC_MASK 0x1FFFF              // 17 bits, N_NODES < 131072

#define G_GROUPS 512
#define EPG (N_EDGES / G_GROUPS)      // 6250 exact

// ---------- edge dtype detection (int64 vs int32) ----------
__global__ __launch_bounds__(64) void k_detect(const int* __restrict__ ei,
                                               int* __restrict__ flag) {
  int v = ei[2 * threadIdx.x + 1];
  unsigned long long m = __ballot(v != 0);
  if (threadIdx.x == 0) *flag = (m == 0ull) ? 1 : 0;  // 1 => int64 layout
}

// ---------- phase 1: per-group LDS histogram over dst buckets ----------
__global__ __launch_bounds__(256) void k_hist(const int* __restrict__ ei,
                                              const int* __restrict__ flag,
                                              int* __restrict__ H) {
  __shared__ int h[NBKT];
  for (int i = threadIdx.x; i < NBKT; i += 256) h[i] = 0;
  __syncthreads();
  int fl = *flag;
  int g = blockIdx.x;
  int e0 = g * EPG, e1 = e0 + EPG;
  for (int e = e0 + threadIdx.x; e < e1; e += 256) {
    int d = fl ? ei[2 * (N_EDGES + e)] : ei[N_EDGES + e];
    d = min(max(d, 0), N_NODES - 1);
    atomicAdd(&h[d >> BSH], 1);
  }
  __syncthreads();
  int* Hrow = H + (size_t)g * NBKT;
  for (int i = threadIdx.x; i < NBKT; i += 256) Hrow[i] = h[i];
}

// ---------- phase 2a: per-bucket exclusive scan over groups ----------
__global__ __launch_bounds__(G_GROUPS) void k_colscan(int* __restrict__ H,
                                                      int* __restrict__ tot) {
  __shared__ int s[G_GROUPS];
  int b = blockIdx.x, t = threadIdx.x;
  int v = H[(size_t)t * NBKT + b];
  s[t] = v;
  __syncthreads();
  for (int off = 1; off < G_GROUPS; off <<= 1) {
    int a = (t >= off) ? s[t - off] : 0;
    __syncthreads();
    s[t] += a;
    __syncthreads();
  }
  H[(size_t)t * NBKT + b] = s[t] - v;     // exclusive prefix within bucket
  if (t == G_GROUPS - 1) tot[b] = s[t];   // bucket total
}

// ---------- phase 2b: exclusive scan of bucket totals -> bin bases ----------
__global__ __launch_bounds__(256) void k_bscan(const int* __restrict__ tot,
                                               int* __restrict__ bbase) {
  __shared__ int s1[256];
  int t = threadIdx.x;
  int c[4];
  int sum1 = 0;
#pragma unroll
  for (int j = 0; j < 4; ++j) {
    int idx = t * 4 + j;
    int cc = (idx < NBKT) ? tot[idx] : 0;
    c[j] = cc;
    sum1 += cc;
  }
  int o1 = sum1;
  s1[t] = sum1;
  __syncthreads();
  for (int off = 1; off < 256; off <<= 1) {
    int a = (t >= off) ? s1[t - off] : 0;
    __syncthreads();
    s1[t] += a;
    __syncthreads();
  }
  int r1 = s1[t] - o1;
#pragma unroll
  for (int j = 0; j < 4; ++j) {
    int idx = t * 4 + j;
    if (idx < NBKT) {
      bbase[idx] = r1;
      r1 += c[j];
    }
  }
}

// ---------- phase 3: rank-scatter into bucket bins (LDS cursors only) ----------
__global__ __launch_bounds__(256) void k_scatter(const int* __restrict__ ei,
                                                 const int* __restrict__ flag,
                                                 const int* __restrict__ H,
                                                 const int* __restrict__ bbase,
                                                 int* __restrict__ binned) {
  __shared__ int cur[NBKT];
  int g = blockIdx.x, t = threadIdx.x;
  const int* Hrow = H + (size_t)g * NBKT;
  for (int i = t; i < NBKT; i += 256) cur[i] = bbase[i] + Hrow[i];
  __syncthreads();
  int fl = *flag;
  int e0 = g * EPG, e1 = e0 + EPG;
  for (int e = e0 + t; e < e1; e += 256) {
    int s, d;
    if (fl) { s = ei[2 * e]; d = ei[2 * (N_EDGES + e)]; }
    else    { s = ei[e];     d = ei[N_EDGES + e]; }
    s = min(max(s, 0), N_NODES - 1);
    d = min(max(d, 0), N_NODES - 1);
    int p = atomicAdd(&cur[d >> BSH], 1);
    p = min(max(p, 0), N_EDGES - 1);
    binned[p] = ((d & 127) << 17) | s;
  }
}

// ---------- tiny prep: ws2 = W2 @ att_src2, wd2 = W2 @ att_dst2 ----------
__global__ __launch_bounds__(64) void k_prep(const float* __restrict__ W2,
                                             const float* __restrict__ as2w,
                                             const float* __restrict__ ad2w,
                                             float* __restrict__ ws2,
                                             float* __restrict__ wd2) {
  int t = threadIdx.x;
  if (t < HID) {
    float s = 0.f, d = 0.f;
    for (int c = 0; c < NCLS; ++c) {
      float wv = W2[t * NCLS + c];
      s += wv * as2w[c];
      d += wv * ad2w[c];
    }
    ws2[t] = s;
    wd2[t] = d;
  }
}

// ---------- layer-1 GEMM (thread-per-row) ----------
__global__ __launch_bounds__(256) void k_gemm1(const float* __restrict__ x,
                                               const float* __restrict__ W,
                                               const float* __restrict__ atts,
                                               const float* __restrict__ attd,
                                               float* __restrict__ h,
                                               float* __restrict__ as_,
                                               float* __restrict__ ad_) {
  int row = blockIdx.x * 256 + threadIdx.x;
  if (row >= N_NODES) return;
  const float4* xr = (const float4*)(x + (size_t)row * F_IN);
  float acc[HID];
#pragma unroll
  for (int f = 0; f < HID; ++f) acc[f] = 0.f;
  for (int k4 = 0; k4 < F_IN / 4; ++k4) {
    float4 xv = xr[k4];
    const float* Wr = W + k4 * 4 * HID;
#pragma unroll
    for (int f = 0; f < HID; ++f)
      acc[f] += xv.x * Wr[f] + xv.y * Wr[HID + f] +
                xv.z * Wr[2 * HID + f] + xv.w * Wr[3 * HID + f];
  }
  float as = 0.f, ad = 0.f;
#pragma unroll
  for (int f = 0; f < HID; ++f) { as += acc[f] * atts[f]; ad += acc[f] * attd[f]; }
  float4* hp = (float4*)(h + (size_t)row * HID);
  hp[0] = make_float4(acc[0], acc[1], acc[2], acc[3]);
  hp[1] = make_float4(acc[4], acc[5], acc[6], acc[7]);
  hp[2] = make_float4(acc[8], acc[9], acc[10], acc[11]);
  hp[3] = make_float4(acc[12], acc[13], acc[14], acc[15]);
  as_[row] = as;
  ad_[row] = ad;
}

// ---------- bucket aggregation via LDS float atomics (ds_add_f32) ----------
// One block per bucket (128 nodes). Self-loop folded into init. acc stride
// 17 floats to spread random-dst lanes across banks (~2/bank, free per m136).
template <bool LAYER1>
__global__ __launch_bounds__(512) void k_bagg(const int* __restrict__ tot,
                                              const int* __restrict__ bbase,
                                              const int* __restrict__ binned,
                                              const float* __restrict__ as_,
                                              const float* __restrict__ ad_,
                                              const float* __restrict__ h,
                                              const float* __restrict__ b1,
                                              const float* __restrict__ ws2,
                                              const float* __restrict__ wd2,
                                              float* __restrict__ outv,
                                              float* __restrict__ as2,
                                              float* __restrict__ ad2) {
  __shared__ float acc[128][17];
  __shared__ float denom[128];
  __shared__ float adloc[128];
  __shared__ int hdr[2];
  int b = blockIdx.x, t = threadIdx.x;
  if (t == 0) {
    hdr[0] = min(max(tot[b], 0), N_EDGES);
    hdr[1] = min(max(bbase[b], 0), N_EDGES - 1);
  }
  if (t < 128) {
    int node = (b << BSH) + t;
    if (node < N_NODES) {
      float as = as_[node], ad = ad_[node];
      adloc[t] = ad;
      float e = as + ad;
      e = e > 0.f ? e : NEG_SLOPE * e;
      denom[t] = __expf(e);           // self-loop weight (no max-shift: |e| small)
    } else {
      adloc[t] = 0.f;
      denom[t] = 1.f;
    }
  }
  __syncthreads();
  // acc init = p_self * h[node]
  for (int i = t; i < 128 * HID; i += 512) {
    int n = i >> 4, f = i & 15;
    int node = (b << BSH) + n;
    acc[n][f] = (node < N_NODES) ? denom[n] * h[(size_t)node * HID + f] : 0.f;
  }
  __syncthreads();
  int nb = hdr[0], base = hdr[1];
  for (int i = t; i < nb; i += 512) {
    int pk = binned[min(base + i, N_EDGES - 1)];
    int dl = (pk >> 17) & 127;
    int src = min(pk & SRC_MASK, N_NODES - 1);
    float e = as_[src] + adloc[dl];
    e = e > 0.f ? e : NEG_SLOPE * e;
    float p = __expf(e);
    atomicAdd(&denom[dl], p);
    const float4* hp = (const float4*)(h + (size_t)src * HID);
    float4 v0 = hp[0], v1 = hp[1], v2 = hp[2], v3 = hp[3];
    atomicAdd(&acc[dl][0],  p * v0.x);
    atomicAdd(&acc[dl][1],  p * v0.y);
    atomicAdd(&acc[dl][2],  p * v0.z);
    atomicAdd(&acc[dl][3],  p * v0.w);
    atomicAdd(&acc[dl][4],  p * v1.x);
    atomicAdd(&acc[dl][5],  p * v1.y);
    atomicAdd(&acc[dl][6],  p * v1.z);
    atomicAdd(&acc[dl][7],  p * v1.w);
    atomicAdd(&acc[dl][8],  p * v2.x);
    atomicAdd(&acc[dl][9],  p * v2.y);
    atomicAdd(&acc[dl][10], p * v2.z);
    atomicAdd(&acc[dl][11], p * v2.w);
    atomicAdd(&acc[dl][12], p * v3.x);
    atomicAdd(&acc[dl][13], p * v3.y);
    atomicAdd(&acc[dl][14], p * v3.z);
    atomicAdd(&acc[dl][15], p * v3.w);
  }
  __syncthreads();
  // epilogue: normalize (+bias/relu for layer 1), write out
  for (int i = t; i < 128 * HID; i += 512) {
    int n = i >> 4, f = i & 15;
    int node = (b << BSH) + n;
    if (node < N_NODES) {
      float val = acc[n][f] / denom[n];
      if (LAYER1) val = fmaxf(val + b1[f], 0.f);
      outv[(size_t)node * HID + f] = val;
      acc[n][f] = val;
    }
  }
  if (LAYER1) {
    __syncthreads();
    // fused layer-2 attention scores: as2 = hr_row . ws2, ad2 = hr_row . wd2
    for (int n = t; n < 128; n += 512) {
      int node = (b << BSH) + n;
      if (node < N_NODES) {
        float rs = 0.f, rd = 0.f;
#pragma unroll
        for (int f = 0; f < HID; ++f) {
          float v = acc[n][f];
          rs += v * ws2[f];
          rd += v * wd2[f];
        }
        as2[node] = rs;
        ad2[node] = rd;
      }
    }
  }
}

// ---------- final: out = log_softmax(agg2 @ W2 + b2), thread-per-node ----------
__global__ __launch_bounds__(256) void k_out(const float* __restrict__ agg2,
                                             const float* __restrict__ W2,
                                             const float* __restrict__ b2,
                                             float* __restrict__ out) {
  int row = blockIdx.x * 256 + threadIdx.x;
  if (row >= N_NODES) return;
  float hv[HID];
  const float4* hp = (const float4*)(agg2 + (size_t)row * HID);
#pragma unroll
  for (int j = 0; j < 4; ++j) {
    float4 v = hp[j];
    hv[4 * j] = v.x; hv[4 * j + 1] = v.y; hv[4 * j + 2] = v.z; hv[4 * j + 3] = v.w;
  }
  float acc[NCLS];
#pragma unroll
  for (int c = 0; c < NCLS; ++c) acc[c] = b2[c];
#pragma unroll
  for (int k = 0; k < HID; ++k) {
    float xv = hv[k];
    const float* Wr = W2 + k * NCLS;
#pragma unroll
    for (int c = 0; c < NCLS; ++c) acc[c] += xv * Wr[c];
  }
  float mx = -1e30f;
#pragma unroll
  for (int c = 0; c < NCLS; ++c) mx = fmaxf(mx, acc[c]);
  float se = 0.f;
#pragma unroll
  for (int c = 0; c < NCLS; ++c) se += __expf(acc[c] - mx);
  float lse = mx + __logf(se);
  float4* op = (float4*)(out + (size_t)row * NCLS);
#pragma unroll
  for (int j = 0; j < 8; ++j)
    op[j] = make_float4(acc[4 * j] - lse, acc[4 * j + 1] - lse,
                        acc[4 * j + 2] - lse, acc[4 * j + 3] - lse);
}

extern "C" void kernel_launch(void* const* d_in, const int* in_sizes, int n_in,
                              void* d_out, int out_size, void* d_ws, size_t ws_size,
                              hipStream_t stream) {
  const float* x    = (const float*)d_in[0];
  const int*   ei   = (const int*)d_in[1];
  const float* W1   = (const float*)d_in[2];
  const float* as1w = (const float*)d_in[3];
  const float* ad1w = (const float*)d_in[4];
  const float* b1   = (const float*)d_in[5];
  const float* W2   = (const float*)d_in[6];
  const float* as2w = (const float*)d_in[7];
  const float* ad2w = (const float*)d_in[8];
  const float* b2   = (const float*)d_in[9];
  float* out = (float*)d_out;

  char* w = (char*)d_ws;
  size_t off = 0;
  auto alloc = [&](size_t bytes) -> char* {
    char* p = w + off;
    off += (bytes + 511) & ~(size_t)511;
    return p;
  };
  int*   flag  = (int*)alloc(4);
  int*   tot   = (int*)alloc((size_t)NBKT * 4);
  int*   bbase = (int*)alloc((size_t)NBKT * 4);
  float* ws2   = (float*)alloc((size_t)HID * 4);
  float* wd2   = (float*)alloc((size_t)HID * 4);
  int*   binned= (int*)alloc((size_t)N_EDGES * 4);          // 12.8 MB (live both layers)
  int*   H     = (int*)alloc((size_t)G_GROUPS * NBKT * 4);  // 1.6 MB
  float* h1    = (float*)alloc((size_t)N_NODES * HID * 4);
  float* as1   = (float*)alloc((size_t)N_NODES * 4);
  float* ad1   = (float*)alloc((size_t)N_NODES * 4);
  float* hr    = (float*)alloc((size_t)N_NODES * HID * 4);
  float* agg2  = (float*)alloc((size_t)N_NODES * HID * 4);
  float* as2   = (float*)alloc((size_t)N_NODES * 4);
  float* ad2   = (float*)alloc((size_t)N_NODES * 4);

  k_detect<<<1, 64, 0, stream>>>(ei, flag);
  k_hist<<<G_GROUPS, 256, 0, stream>>>(ei, flag, H);
  k_colscan<<<NBKT, G_GROUPS, 0, stream>>>(H, tot);
  k_bscan<<<1, 256, 0, stream>>>(tot, bbase);
  k_scatter<<<G_GROUPS, 256, 0, stream>>>(ei, flag, H, bbase, binned);
  k_gemm1<<<(N_NODES + 255) / 256, 256, 0, stream>>>(x, W1, as1w, ad1w, h1, as1, ad1);
  k_prep<<<1, 64, 0, stream>>>(W2, as2w, ad2w, ws2, wd2);
  k_bagg<true><<<NBKT, 512, 0, stream>>>(tot, bbase, binned, as1, ad1, h1,
                                         b1, ws2, wd2, hr, as2, ad2);
  k_bagg<false><<<NBKT, 512, 0, stream>>>(tot, bbase, binned, as2, ad2, hr,
                                          nullptr, nullptr, nullptr,
                                          agg2, nullptr, nullptr);
  k_out<<<(N_NODES + 255) / 256, 256, 0, stream>>>(agg2, W2, b2, out);
}

// Round 8
// 362.024 us; speedup vs baseline: 2.4677x; 2.4677x over previous
//
#include <hip/hip_runtime.h>
#include <math.h>

#define N_NODES 100000
#define N_EDGES 3200000
#define N_TOT   (N_EDGES + N_NODES)
#define F_IN    512
#define HID     16
#define NCLS    32
#define NEG_SLOPE 0.2f

#define BSH   7                       // bucket shift: 128 nodes per bucket
#define NBKT  ((N_NODES + 127) / 128) // 782
#define SRC_MASK 0x1FFFF              // 17 bits, N_NODES < 131072

#define G_GROUPS 512
#define EPG (N_EDGES / G_GROUPS)      // 6250 exact

// ---------- edge dtype detection (int64 vs int32) ----------
__global__ __launch_bounds__(64) void k_detect(const int* __restrict__ ei,
                                               int* __restrict__ flag) {
  int v = ei[2 * threadIdx.x + 1];
  unsigned long long m = __ballot(v != 0);
  if (threadIdx.x == 0) *flag = (m == 0ull) ? 1 : 0;  // 1 => int64 layout
}

// ---------- phase 1: per-group LDS histogram over dst buckets ----------
__global__ __launch_bounds__(256) void k_hist(const int* __restrict__ ei,
                                              const int* __restrict__ flag,
                                              int* __restrict__ H) {
  __shared__ int h[NBKT];
  for (int i = threadIdx.x; i < NBKT; i += 256) h[i] = 0;
  __syncthreads();
  int fl = *flag;
  int g = blockIdx.x;
  int e0 = g * EPG, e1 = e0 + EPG;
  for (int e = e0 + threadIdx.x; e < e1; e += 256) {
    int d = fl ? ei[2 * (N_EDGES + e)] : ei[N_EDGES + e];
    d = min(max(d, 0), N_NODES - 1);
    atomicAdd(&h[d >> BSH], 1);
  }
  __syncthreads();
  int* Hrow = H + (size_t)g * NBKT;
  for (int i = threadIdx.x; i < NBKT; i += 256) Hrow[i] = h[i];
}

// ---------- phase 2a: per-bucket exclusive scan over groups ----------
__global__ __launch_bounds__(G_GROUPS) void k_colscan(int* __restrict__ H,
                                                      int* __restrict__ tot) {
  __shared__ int s[G_GROUPS];
  int b = blockIdx.x, t = threadIdx.x;
  int v = H[(size_t)t * NBKT + b];
  s[t] = v;
  __syncthreads();
  for (int off = 1; off < G_GROUPS; off <<= 1) {
    int a = (t >= off) ? s[t - off] : 0;
    __syncthreads();
    s[t] += a;
    __syncthreads();
  }
  H[(size_t)t * NBKT + b] = s[t] - v;     // exclusive prefix within bucket
  if (t == G_GROUPS - 1) tot[b] = s[t];   // bucket total
}

// ---------- phase 2b: scan bucket totals ----------
__global__ __launch_bounds__(256) void k_bscan(const int* __restrict__ tot,
                                               int* __restrict__ bbase,
                                               int* __restrict__ cbase,
                                               int* __restrict__ offs) {
  __shared__ int s1[256], s2[256];
  int t = threadIdx.x;
  int c[4], vn[4];
  int sum1 = 0, sum2 = 0;
#pragma unroll
  for (int j = 0; j < 4; ++j) {
    int idx = t * 4 + j;
    int cc = 0, vv = 0;
    if (idx < NBKT) {
      cc = tot[idx];
      int lo = idx << BSH;
      vv = min(128, N_NODES - lo);
    }
    c[j] = cc; vn[j] = vv;
    sum1 += cc; sum2 += cc + vv;
  }
  int o1 = sum1, o2 = sum2;
  s1[t] = sum1; s2[t] = sum2;
  __syncthreads();
  for (int off = 1; off < 256; off <<= 1) {
    int a = 0, b = 0;
    if (t >= off) { a = s1[t - off]; b = s2[t - off]; }
    __syncthreads();
    s1[t] += a; s2[t] += b;
    __syncthreads();
  }
  int r1 = s1[t] - o1;
  int r2 = s2[t] - o2;
#pragma unroll
  for (int j = 0; j < 4; ++j) {
    int idx = t * 4 + j;
    if (idx < NBKT) {
      bbase[idx] = r1; cbase[idx] = r2;
      r1 += c[j];
      r2 += c[j] + vn[j];
    }
  }
  if (t == 0) offs[N_NODES] = N_TOT;
}

// ---------- phase 3: rank-scatter into bucket bins (LDS cursors only) ----------
__global__ __launch_bounds__(256) void k_scatter(const int* __restrict__ ei,
                                                 const int* __restrict__ flag,
                                                 const int* __restrict__ H,
                                                 const int* __restrict__ bbase,
                                                 int* __restrict__ binned) {
  __shared__ int cur[NBKT];
  int g = blockIdx.x, t = threadIdx.x;
  const int* Hrow = H + (size_t)g * NBKT;
  for (int i = t; i < NBKT; i += 256) cur[i] = bbase[i] + Hrow[i];
  __syncthreads();
  int fl = *flag;
  int e0 = g * EPG, e1 = e0 + EPG;
  for (int e = e0 + t; e < e1; e += 256) {
    int s, d;
    if (fl) { s = ei[2 * e]; d = ei[2 * (N_EDGES + e)]; }
    else    { s = ei[e];     d = ei[N_EDGES + e]; }
    s = min(max(s, 0), N_NODES - 1);
    d = min(max(d, 0), N_NODES - 1);
    int p = atomicAdd(&cur[d >> BSH], 1);
    p = min(max(p, 0), N_EDGES - 1);
    binned[p] = ((d & 127) << 17) | s;
  }
}

// ---------- per-bucket counting sort in LDS -> CSR offs + srcS ----------
__global__ __launch_bounds__(256) void k_bucket(const int* __restrict__ tot,
                                                const int* __restrict__ bbase,
                                                const int* __restrict__ cbase,
                                                const int* __restrict__ binned,
                                                int* __restrict__ offs,
                                                int* __restrict__ srcS) {
  __shared__ int cnt[128], cur[128], sc[128];
  __shared__ int hdr[3];
  int b = blockIdx.x, t = threadIdx.x;
  if (t == 0) {
    hdr[0] = min(max(tot[b], 0), N_EDGES);
    hdr[1] = min(max(bbase[b], 0), N_EDGES - 1);
    hdr[2] = min(max(cbase[b], 0), N_TOT - 1);
  }
  if (t < 128) cnt[t] = 0;
  __syncthreads();
  int nb = hdr[0], base = hdr[1], cb = hdr[2];

  for (int i = t; i < nb; i += 256) {
    int pk = binned[min(base + i, N_EDGES - 1)];
    atomicAdd(&cnt[(pk >> 17) & 127], 1);
  }
  __syncthreads();

  int node = (b << BSH) + t;
  int myv = 0;
  if (t < 128) myv = (node < N_NODES) ? cnt[t] + 1 : 0;  // +1 self loop
  if (t < 128) sc[t] = myv;
  __syncthreads();
  for (int off = 1; off < 128; off <<= 1) {
    int v = 0;
    if (t < 128 && t >= off) v = sc[t - off];
    __syncthreads();
    if (t < 128) sc[t] += v;
    __syncthreads();
  }
  if (t < 128 && node < N_NODES) {
    int lofs = sc[t] - myv;
    int o = min(cb + lofs, N_TOT - 1);
    offs[node] = o;
    srcS[o] = node;                  // self-loop occupies slot 0
    cur[t] = lofs + 1;
  }
  __syncthreads();

  for (int i = t; i < nb; i += 256) {
    int pk = binned[min(base + i, N_EDGES - 1)];
    int p = atomicAdd(&cur[(pk >> 17) & 127], 1);
    srcS[min(cb + p, N_TOT - 1)] = pk & SRC_MASK;
  }
}

// ---------- tiny prep: ws2 = W2 @ att_src2, wd2 = W2 @ att_dst2 ----------
__global__ __launch_bounds__(64) void k_prep(const float* __restrict__ W2,
                                             const float* __restrict__ as2w,
                                             const float* __restrict__ ad2w,
                                             float* __restrict__ ws2,
                                             float* __restrict__ wd2) {
  int t = threadIdx.x;
  if (t < HID) {
    float s = 0.f, d = 0.f;
    for (int c = 0; c < NCLS; ++c) {
      float wv = W2[t * NCLS + c];
      s += wv * as2w[c];
      d += wv * ad2w[c];
    }
    ws2[t] = s;
    wd2[t] = d;
  }
}

// ---------- layer-1 GEMM (thread-per-row) ----------
__global__ __launch_bounds__(256) void k_gemm1(const float* __restrict__ x,
                                               const float* __restrict__ W,
                                               const float* __restrict__ atts,
                                               const float* __restrict__ attd,
                                               float* __restrict__ h,
                                               float* __restrict__ as_,
                                               float* __restrict__ ad_) {
  int row = blockIdx.x * 256 + threadIdx.x;
  if (row >= N_NODES) return;
  const float4* xr = (const float4*)(x + (size_t)row * F_IN);
  float acc[HID];
#pragma unroll
  for (int f = 0; f < HID; ++f) acc[f] = 0.f;
  for (int k4 = 0; k4 < F_IN / 4; ++k4) {
    float4 xv = xr[k4];
    const float* Wr = W + k4 * 4 * HID;
#pragma unroll
    for (int f = 0; f < HID; ++f)
      acc[f] += xv.x * Wr[f] + xv.y * Wr[HID + f] +
                xv.z * Wr[2 * HID + f] + xv.w * Wr[3 * HID + f];
  }
  float as = 0.f, ad = 0.f;
#pragma unroll
  for (int f = 0; f < HID; ++f) { as += acc[f] * atts[f]; ad += acc[f] * attd[f]; }
  float4* hp = (float4*)(h + (size_t)row * HID);
  hp[0] = make_float4(acc[0], acc[1], acc[2], acc[3]);
  hp[1] = make_float4(acc[4], acc[5], acc[6], acc[7]);
  hp[2] = make_float4(acc[8], acc[9], acc[10], acc[11]);
  hp[3] = make_float4(acc[12], acc[13], acc[14], acc[15]);
  as_[row] = as;
  ad_[row] = ad;
}

// ---------- fused aggregate: single-sweep softmax+gather, float4 lanes ----
// Wave per node. Lane = (edge-slot lane>>2, feature-quad lane&3): each step
// processes 16 edges, one float4 h-load + 4 fmas per lane. All shuffles run
// with the FULL wave active (clamped source lane, predicated accumulate) —
// divergent-source ds_bpermute is undefined (round-5 bug).
template <bool LAYER1>
__global__ __launch_bounds__(256) void k_agg(const int* __restrict__ offs,
                                             const int* __restrict__ srcS,
                                             const float* __restrict__ as_,
                                             const float* __restrict__ ad_,
                                             const float* __restrict__ h,
                                             const float* __restrict__ b1,
                                             const float* __restrict__ ws2,
                                             const float* __restrict__ wd2,
                                             float* __restrict__ outv,
                                             float* __restrict__ as2,
                                             float* __restrict__ ad2) {
  int node = blockIdx.x * 4 + (threadIdx.x >> 6);
  if (node >= N_NODES) return;
  int lane = threadIdx.x & 63;
  int esub = lane >> 2;     // 16 edge slots per step
  int f4 = lane & 3;        // feature quad
  int beg = offs[node];
  int end = offs[node + 1];
  beg = min(max(beg, 0), N_TOT);
  end = min(max(end, beg), N_TOT);
  float ad = ad_[node];

  float s_lane = 0.f;
  float4 acc = make_float4(0.f, 0.f, 0.f, 0.f);
  for (int i0 = beg; i0 < end; i0 += 64) {
    int nb = min(64, end - i0);
    int sn = 0;
    float p = 0.f;
    if (lane < nb) {
      sn = min(max(srcS[i0 + lane], 0), N_NODES - 1);
      float e = as_[sn] + ad;
      e = e > 0.f ? e : NEG_SLOPE * e;
      p = __expf(e);           // no max-shift: |e| <= ~12, exp safe in fp32
    }
    s_lane += p;
    int steps = (nb + 15) >> 4;
    for (int t = 0; t < steps; ++t) {
      int j = esub + 16 * t;
      int jj = min(j, nb - 1);           // clamp so source lane is valid
      float pj = __shfl(p, jj);          // full wave active
      int snj = __shfl(sn, jj);
      if (j < nb) {
        float4 v = ((const float4*)(h + (size_t)snj * HID))[f4];
        acc.x += pj * v.x;
        acc.y += pj * v.y;
        acc.z += pj * v.z;
        acc.w += pj * v.w;
      }
    }
  }
  // total denom across all 64 lanes
#pragma unroll
  for (int off = 1; off < 64; off <<= 1) s_lane += __shfl_xor(s_lane, off);
  // sum acc across the 16 edge slots (lanes with equal f4)
#pragma unroll
  for (int off = 4; off < 64; off <<= 1) {
    acc.x += __shfl_xor(acc.x, off);
    acc.y += __shfl_xor(acc.y, off);
    acc.z += __shfl_xor(acc.z, off);
    acc.w += __shfl_xor(acc.w, off);
  }
  float inv_s = 1.f / s_lane;

  if (LAYER1) {
    float4 bv = ((const float4*)b1)[f4];
    float4 val;
    val.x = fmaxf(acc.x * inv_s + bv.x, 0.f);
    val.y = fmaxf(acc.y * inv_s + bv.y, 0.f);
    val.z = fmaxf(acc.z * inv_s + bv.z, 0.f);
    val.w = fmaxf(acc.w * inv_s + bv.w, 0.f);
    if (lane < 4) ((float4*)(outv + (size_t)node * HID))[lane] = val;
    // fused layer-2 attention scores: as2 = hr_row . ws2, ad2 = hr_row . wd2
    float4 w_s = ((const float4*)ws2)[f4];
    float4 w_d = ((const float4*)wd2)[f4];
    float rs = val.x * w_s.x + val.y * w_s.y + val.z * w_s.z + val.w * w_s.w;
    float rd = val.x * w_d.x + val.y * w_d.y + val.z * w_d.z + val.w * w_d.w;
    rs += __shfl_xor(rs, 1); rs += __shfl_xor(rs, 2);
    rd += __shfl_xor(rd, 1); rd += __shfl_xor(rd, 2);
    if (lane == 0) { as2[node] = rs; ad2[node] = rd; }
  } else {
    float4 val;
    val.x = acc.x * inv_s;
    val.y = acc.y * inv_s;
    val.z = acc.z * inv_s;
    val.w = acc.w * inv_s;
    if (lane < 4) ((float4*)(outv + (size_t)node * HID))[lane] = val;
  }
}

// ---------- final: out = log_softmax(agg2 @ W2 + b2), thread-per-node ----------
__global__ __launch_bounds__(256) void k_out(const float* __restrict__ agg2,
                                             const float* __restrict__ W2,
                                             const float* __restrict__ b2,
                                             float* __restrict__ out) {
  int row = blockIdx.x * 256 + threadIdx.x;
  if (row >= N_NODES) return;
  float hv[HID];
  const float4* hp = (const float4*)(agg2 + (size_t)row * HID);
#pragma unroll
  for (int j = 0; j < 4; ++j) {
    float4 v = hp[j];
    hv[4 * j] = v.x; hv[4 * j + 1] = v.y; hv[4 * j + 2] = v.z; hv[4 * j + 3] = v.w;
  }
  float acc[NCLS];
#pragma unroll
  for (int c = 0; c < NCLS; ++c) acc[c] = b2[c];
#pragma unroll
  for (int k = 0; k < HID; ++k) {
    float xv = hv[k];
    const float* Wr = W2 + k * NCLS;
#pragma unroll
    for (int c = 0; c < NCLS; ++c) acc[c] += xv * Wr[c];
  }
  float mx = -1e30f;
#pragma unroll
  for (int c = 0; c < NCLS; ++c) mx = fmaxf(mx, acc[c]);
  float se = 0.f;
#pragma unroll
  for (int c = 0; c < NCLS; ++c) se += __expf(acc[c] - mx);
  float lse = mx + __logf(se);
  float4* op = (float4*)(out + (size_t)row * NCLS);
#pragma unroll
  for (int j = 0; j < 8; ++j)
    op[j] = make_float4(acc[4 * j] - lse, acc[4 * j + 1] - lse,
                        acc[4 * j + 2] - lse, acc[4 * j + 3] - lse);
}

extern "C" void kernel_launch(void* const* d_in, const int* in_sizes, int n_in,
                              void* d_out, int out_size, void* d_ws, size_t ws_size,
                              hipStream_t stream) {
  const float* x    = (const float*)d_in[0];
  const int*   ei   = (const int*)d_in[1];
  const float* W1   = (const float*)d_in[2];
  const float* as1w = (const float*)d_in[3];
  const float* ad1w = (const float*)d_in[4];
  const float* b1   = (const float*)d_in[5];
  const float* W2   = (const float*)d_in[6];
  const float* as2w = (const float*)d_in[7];
  const float* ad2w = (const float*)d_in[8];
  const float* b2   = (const float*)d_in[9];
  float* out = (float*)d_out;

  char* w = (char*)d_ws;
  size_t off = 0;
  auto alloc = [&](size_t bytes) -> char* {
    char* p = w + off;
    off += (bytes + 511) & ~(size_t)511;
    return p;
  };
  int*   flag  = (int*)alloc(4);
  int*   tot   = (int*)alloc((size_t)NBKT * 4);
  int*   bbase = (int*)alloc((size_t)NBKT * 4);
  int*   cbase = (int*)alloc((size_t)NBKT * 4);
  int*   offs  = (int*)alloc((size_t)(N_NODES + 1) * 4);
  int*   srcS  = (int*)alloc((size_t)N_TOT * 4);
  float* ws2   = (float*)alloc((size_t)HID * 4);
  float* wd2   = (float*)alloc((size_t)HID * 4);

  // union region: {binned 12.8MB + H 1.6MB} (CSR build) vs layer arrays.
  // binned/H are dead before k_gemm1 writes h1 (stream-ordered).
  size_t region_begin = off;
  int* binned = (int*)alloc((size_t)N_EDGES * 4);
  int* H      = (int*)alloc((size_t)G_GROUPS * NBKT * 4);
  off = region_begin;
  float* h1   = (float*)alloc((size_t)N_NODES * HID * 4);
  float* as1  = (float*)alloc((size_t)N_NODES * 4);
  float* ad1  = (float*)alloc((size_t)N_NODES * 4);
  float* hr   = (float*)alloc((size_t)N_NODES * HID * 4);
  float* agg2 = (float*)alloc((size_t)N_NODES * HID * 4);
  float* as2  = (float*)alloc((size_t)N_NODES * 4);
  float* ad2  = (float*)alloc((size_t)N_NODES * 4);

  k_detect<<<1, 64, 0, stream>>>(ei, flag);
  k_hist<<<G_GROUPS, 256, 0, stream>>>(ei, flag, H);
  k_colscan<<<NBKT, G_GROUPS, 0, stream>>>(H, tot);
  k_bscan<<<1, 256, 0, stream>>>(tot, bbase, cbase, offs);
  k_scatter<<<G_GROUPS, 256, 0, stream>>>(ei, flag, H, bbase, binned);
  k_bucket<<<NBKT, 256, 0, stream>>>(tot, bbase, cbase, binned, offs, srcS);
  k_gemm1<<<(N_NODES + 255) / 256, 256, 0, stream>>>(x, W1, as1w, ad1w, h1, as1, ad1);
  k_prep<<<1, 64, 0, stream>>>(W2, as2w, ad2w, ws2, wd2);
  k_agg<true><<<(N_NODES + 3) / 4, 256, 0, stream>>>(offs, srcS, as1, ad1, h1,
                                                     b1, ws2, wd2, hr, as2, ad2);
  k_agg<false><<<(N_NODES + 3) / 4, 256, 0, stream>>>(offs, srcS, as2, ad2, hr,
                                                      nullptr, nullptr, nullptr,
                                                      agg2, nullptr, nullptr);
  k_out<<<(N_NODES + 255) / 256, 256, 0, stream>>>(agg2, W2, b2, out);
}

// Round 9
// 359.846 us; speedup vs baseline: 2.4826x; 1.0061x over previous
//
#include <hip/hip_runtime.h>
#include <math.h>

#define N_NODES 100000
#define N_EDGES 3200000
#define N_TOT   (N_EDGES + N_NODES)
#define F_IN    512
#define HID     16
#define NCLS    32
#define NEG_SLOPE 0.2f

#define BSH   7                       // bucket shift: 128 nodes per bucket
#define NBKT  ((N_NODES + 127) / 128) // 782
#define SRC_MASK 0x1FFFF              // 17 bits, N_NODES < 131072

#define G_GROUPS 512
#define EPG (N_EDGES / G_GROUPS)      // 6250 exact

// ---------- edge dtype detection (int64 vs int32) ----------
__global__ __launch_bounds__(64) void k_detect(const int* __restrict__ ei,
                                               int* __restrict__ flag) {
  int v = ei[2 * threadIdx.x + 1];
  unsigned long long m = __ballot(v != 0);
  if (threadIdx.x == 0) *flag = (m == 0ull) ? 1 : 0;  // 1 => int64 layout
}

// ---------- phase 1: per-group LDS histogram over dst buckets ----------
__global__ __launch_bounds__(256) void k_hist(const int* __restrict__ ei,
                                              const int* __restrict__ flag,
                                              int* __restrict__ H) {
  __shared__ int h[NBKT];
  for (int i = threadIdx.x; i < NBKT; i += 256) h[i] = 0;
  __syncthreads();
  int fl = *flag;
  int g = blockIdx.x;
  int e0 = g * EPG, e1 = e0 + EPG;
  for (int e = e0 + threadIdx.x; e < e1; e += 256) {
    int d = fl ? ei[2 * (N_EDGES + e)] : ei[N_EDGES + e];
    d = min(max(d, 0), N_NODES - 1);
    atomicAdd(&h[d >> BSH], 1);
  }
  __syncthreads();
  int* Hrow = H + (size_t)g * NBKT;
  for (int i = threadIdx.x; i < NBKT; i += 256) Hrow[i] = h[i];
}

// ---------- phase 2a: per-bucket exclusive scan over groups ----------
__global__ __launch_bounds__(G_GROUPS) void k_colscan(int* __restrict__ H,
                                                      int* __restrict__ tot) {
  __shared__ int s[G_GROUPS];
  int b = blockIdx.x, t = threadIdx.x;
  int v = H[(size_t)t * NBKT + b];
  s[t] = v;
  __syncthreads();
  for (int off = 1; off < G_GROUPS; off <<= 1) {
    int a = (t >= off) ? s[t - off] : 0;
    __syncthreads();
    s[t] += a;
    __syncthreads();
  }
  H[(size_t)t * NBKT + b] = s[t] - v;     // exclusive prefix within bucket
  if (t == G_GROUPS - 1) tot[b] = s[t];   // bucket total
}

// ---------- phase 2b: scan bucket totals ----------
__global__ __launch_bounds__(256) void k_bscan(const int* __restrict__ tot,
                                               int* __restrict__ bbase,
                                               int* __restrict__ cbase,
                                               int* __restrict__ offs) {
  __shared__ int s1[256], s2[256];
  int t = threadIdx.x;
  int c[4], vn[4];
  int sum1 = 0, sum2 = 0;
#pragma unroll
  for (int j = 0; j < 4; ++j) {
    int idx = t * 4 + j;
    int cc = 0, vv = 0;
    if (idx < NBKT) {
      cc = tot[idx];
      int lo = idx << BSH;
      vv = min(128, N_NODES - lo);
    }
    c[j] = cc; vn[j] = vv;
    sum1 += cc; sum2 += cc + vv;
  }
  int o1 = sum1, o2 = sum2;
  s1[t] = sum1; s2[t] = sum2;
  __syncthreads();
  for (int off = 1; off < 256; off <<= 1) {
    int a = 0, b = 0;
    if (t >= off) { a = s1[t - off]; b = s2[t - off]; }
    __syncthreads();
    s1[t] += a; s2[t] += b;
    __syncthreads();
  }
  int r1 = s1[t] - o1;
  int r2 = s2[t] - o2;
#pragma unroll
  for (int j = 0; j < 4; ++j) {
    int idx = t * 4 + j;
    if (idx < NBKT) {
      bbase[idx] = r1; cbase[idx] = r2;
      r1 += c[j];
      r2 += c[j] + vn[j];
    }
  }
  if (t == 0) offs[N_NODES] = N_TOT;
}

// ---------- phase 3: rank-scatter into bucket bins (LDS cursors only) ----------
__global__ __launch_bounds__(256) void k_scatter(const int* __restrict__ ei,
                                                 const int* __restrict__ flag,
                                                 const int* __restrict__ H,
                                                 const int* __restrict__ bbase,
                                                 int* __restrict__ binned) {
  __shared__ int cur[NBKT];
  int g = blockIdx.x, t = threadIdx.x;
  const int* Hrow = H + (size_t)g * NBKT;
  for (int i = t; i < NBKT; i += 256) cur[i] = bbase[i] + Hrow[i];
  __syncthreads();
  int fl = *flag;
  int e0 = g * EPG, e1 = e0 + EPG;
  for (int e = e0 + t; e < e1; e += 256) {
    int s, d;
    if (fl) { s = ei[2 * e]; d = ei[2 * (N_EDGES + e)]; }
    else    { s = ei[e];     d = ei[N_EDGES + e]; }
    s = min(max(s, 0), N_NODES - 1);
    d = min(max(d, 0), N_NODES - 1);
    int p = atomicAdd(&cur[d >> BSH], 1);
    p = min(max(p, 0), N_EDGES - 1);
    binned[p] = ((d & 127) << 17) | s;
  }
}

// ---------- per-bucket counting sort in LDS -> CSR offs + srcS ----------
__global__ __launch_bounds__(256) void k_bucket(const int* __restrict__ tot,
                                                const int* __restrict__ bbase,
                                                const int* __restrict__ cbase,
                                                const int* __restrict__ binned,
                                                int* __restrict__ offs,
                                                int* __restrict__ srcS) {
  __shared__ int cnt[128], cur[128], sc[128];
  __shared__ int hdr[3];
  int b = blockIdx.x, t = threadIdx.x;
  if (t == 0) {
    hdr[0] = min(max(tot[b], 0), N_EDGES);
    hdr[1] = min(max(bbase[b], 0), N_EDGES - 1);
    hdr[2] = min(max(cbase[b], 0), N_TOT - 1);
  }
  if (t < 128) cnt[t] = 0;
  __syncthreads();
  int nb = hdr[0], base = hdr[1], cb = hdr[2];

  for (int i = t; i < nb; i += 256) {
    int pk = binned[min(base + i, N_EDGES - 1)];
    atomicAdd(&cnt[(pk >> 17) & 127], 1);
  }
  __syncthreads();

  int node = (b << BSH) + t;
  int myv = 0;
  if (t < 128) myv = (node < N_NODES) ? cnt[t] + 1 : 0;  // +1 self loop
  if (t < 128) sc[t] = myv;
  __syncthreads();
  for (int off = 1; off < 128; off <<= 1) {
    int v = 0;
    if (t < 128 && t >= off) v = sc[t - off];
    __syncthreads();
    if (t < 128) sc[t] += v;
    __syncthreads();
  }
  if (t < 128 && node < N_NODES) {
    int lofs = sc[t] - myv;
    int o = min(cb + lofs, N_TOT - 1);
    offs[node] = o;
    srcS[o] = node;                  // self-loop occupies slot 0
    cur[t] = lofs + 1;
  }
  __syncthreads();

  for (int i = t; i < nb; i += 256) {
    int pk = binned[min(base + i, N_EDGES - 1)];
    int p = atomicAdd(&cur[(pk >> 17) & 127], 1);
    srcS[min(cb + p, N_TOT - 1)] = pk & SRC_MASK;
  }
}

// ---------- tiny prep: ws2 = W2 @ att_src2, wd2 = W2 @ att_dst2 ----------
__global__ __launch_bounds__(64) void k_prep(const float* __restrict__ W2,
                                             const float* __restrict__ as2w,
                                             const float* __restrict__ ad2w,
                                             float* __restrict__ ws2,
                                             float* __restrict__ wd2) {
  int t = threadIdx.x;
  if (t < HID) {
    float s = 0.f, d = 0.f;
    for (int c = 0; c < NCLS; ++c) {
      float wv = W2[t * NCLS + c];
      s += wv * as2w[c];
      d += wv * ad2w[c];
    }
    ws2[t] = s;
    wd2[t] = d;
  }
}

// ---------- layer-1 GEMM: 4 waves/block, per-wave K-quarter ----------
// Wave q handles rows [row0,row0+64) x k in [128q,128q+128): k-range is
// wave-uniform so W stays on the scalar (s_load) path; lane = row. 16-deep
// float4 load batches keep ~320 loads in flight per CU (20 waves/CU) to
// hide HBM/L3 latency (round-8 profile: 6 waves/CU, latency-bound 145us).
__global__ __launch_bounds__(256) void k_gemm1(const float* __restrict__ x,
                                               const float* __restrict__ W,
                                               const float* __restrict__ atts,
                                               const float* __restrict__ attd,
                                               float* __restrict__ h,
                                               float* __restrict__ as_,
                                               float* __restrict__ ad_) {
  __shared__ float pacc[4][64][17];   // padded: lane/lane+32 2-way only (free)
  int q = threadIdx.x >> 6;           // wave id = k-quarter (wave-uniform)
  int lane = threadIdx.x & 63;
  int row0 = blockIdx.x * 64;
  int row = row0 + lane;
  int rowc = min(row, N_NODES - 1);
  const float4* xr = (const float4*)(x + (size_t)rowc * F_IN) + q * 32;
  const float* Wq = W + q * 128 * HID;
  float acc[HID];
#pragma unroll
  for (int f = 0; f < HID; ++f) acc[f] = 0.f;
#pragma unroll
  for (int ob = 0; ob < 2; ++ob) {
    float4 xv[16];
#pragma unroll
    for (int u = 0; u < 16; ++u) xv[u] = xr[ob * 16 + u];
#pragma unroll
    for (int u = 0; u < 16; ++u) {
      const float* Wr = Wq + (ob * 64 + u * 4) * HID;
#pragma unroll
      for (int f = 0; f < HID; ++f)
        acc[f] += xv[u].x * Wr[f] + xv[u].y * Wr[HID + f] +
                  xv[u].z * Wr[2 * HID + f] + xv[u].w * Wr[3 * HID + f];
    }
  }
#pragma unroll
  for (int f = 0; f < HID; ++f) pacc[q][lane][f] = acc[f];
  __syncthreads();
  // reduce across the 4 k-quarters: thread -> (row r, feature quad j)
  int r = threadIdx.x >> 2, j = threadIdx.x & 3;
  float4 s;
  s.x = pacc[0][r][j * 4 + 0] + pacc[1][r][j * 4 + 0] +
        pacc[2][r][j * 4 + 0] + pacc[3][r][j * 4 + 0];
  s.y = pacc[0][r][j * 4 + 1] + pacc[1][r][j * 4 + 1] +
        pacc[2][r][j * 4 + 1] + pacc[3][r][j * 4 + 1];
  s.z = pacc[0][r][j * 4 + 2] + pacc[1][r][j * 4 + 2] +
        pacc[2][r][j * 4 + 2] + pacc[3][r][j * 4 + 2];
  s.w = pacc[0][r][j * 4 + 3] + pacc[1][r][j * 4 + 3] +
        pacc[2][r][j * 4 + 3] + pacc[3][r][j * 4 + 3];
  int orow = row0 + r;
  if (orow < N_NODES) ((float4*)(h + (size_t)orow * HID))[j] = s;
  __syncthreads();
  pacc[0][r][j * 4 + 0] = s.x;
  pacc[0][r][j * 4 + 1] = s.y;
  pacc[0][r][j * 4 + 2] = s.z;
  pacc[0][r][j * 4 + 3] = s.w;
  __syncthreads();
  if (threadIdx.x < 64 && row < N_NODES) {
    float as = 0.f, ad = 0.f;
#pragma unroll
    for (int f = 0; f < HID; ++f) {
      float v = pacc[0][lane][f];
      as += v * atts[f];
      ad += v * attd[f];
    }
    as_[row] = as;
    ad_[row] = ad;
  }
}

// ---------- fused aggregate: single-sweep softmax+gather, float4 lanes ----
// Wave per node. Lane = (edge-slot lane>>2, feature-quad lane&3): each step
// processes 16 edges, one float4 h-load + 4 fmas per lane. All shuffles run
// with the FULL wave active (clamped source lane, predicated accumulate) —
// divergent-source ds_bpermute is undefined (round-5 bug).
template <bool LAYER1>
__global__ __launch_bounds__(256) void k_agg(const int* __restrict__ offs,
                                             const int* __restrict__ srcS,
                                             const float* __restrict__ as_,
                                             const float* __restrict__ ad_,
                                             const float* __restrict__ h,
                                             const float* __restrict__ b1,
                                             const float* __restrict__ ws2,
                                             const float* __restrict__ wd2,
                                             float* __restrict__ outv,
                                             float* __restrict__ as2,
                                             float* __restrict__ ad2) {
  int node = blockIdx.x * 4 + (threadIdx.x >> 6);
  if (node >= N_NODES) return;
  int lane = threadIdx.x & 63;
  int esub = lane >> 2;     // 16 edge slots per step
  int f4 = lane & 3;        // feature quad
  int beg = offs[node];
  int end = offs[node + 1];
  beg = min(max(beg, 0), N_TOT);
  end = min(max(end, beg), N_TOT);
  float ad = ad_[node];

  float s_lane = 0.f;
  float4 acc = make_float4(0.f, 0.f, 0.f, 0.f);
  for (int i0 = beg; i0 < end; i0 += 64) {
    int nb = min(64, end - i0);
    int sn = 0;
    float p = 0.f;
    if (lane < nb) {
      sn = min(max(srcS[i0 + lane], 0), N_NODES - 1);
      float e = as_[sn] + ad;
      e = e > 0.f ? e : NEG_SLOPE * e;
      p = __expf(e);           // no max-shift: |e| <= ~12, exp safe in fp32
    }
    s_lane += p;
    int steps = (nb + 15) >> 4;
    for (int t = 0; t < steps; ++t) {
      int j = esub + 16 * t;
      int jj = min(j, nb - 1);           // clamp so source lane is valid
      float pj = __shfl(p, jj);          // full wave active
      int snj = __shfl(sn, jj);
      if (j < nb) {
        float4 v = ((const float4*)(h + (size_t)snj * HID))[f4];
        acc.x += pj * v.x;
        acc.y += pj * v.y;
        acc.z += pj * v.z;
        acc.w += pj * v.w;
      }
    }
  }
  // total denom across all 64 lanes
#pragma unroll
  for (int off = 1; off < 64; off <<= 1) s_lane += __shfl_xor(s_lane, off);
  // sum acc across the 16 edge slots (lanes with equal f4)
#pragma unroll
  for (int off = 4; off < 64; off <<= 1) {
    acc.x += __shfl_xor(acc.x, off);
    acc.y += __shfl_xor(acc.y, off);
    acc.z += __shfl_xor(acc.z, off);
    acc.w += __shfl_xor(acc.w, off);
  }
  float inv_s = 1.f / s_lane;

  if (LAYER1) {
    float4 bv = ((const float4*)b1)[f4];
    float4 val;
    val.x = fmaxf(acc.x * inv_s + bv.x, 0.f);
    val.y = fmaxf(acc.y * inv_s + bv.y, 0.f);
    val.z = fmaxf(acc.z * inv_s + bv.z, 0.f);
    val.w = fmaxf(acc.w * inv_s + bv.w, 0.f);
    if (lane < 4) ((float4*)(outv + (size_t)node * HID))[lane] = val;
    // fused layer-2 attention scores: as2 = hr_row . ws2, ad2 = hr_row . wd2
    float4 w_s = ((const float4*)ws2)[f4];
    float4 w_d = ((const float4*)wd2)[f4];
    float rs = val.x * w_s.x + val.y * w_s.y + val.z * w_s.z + val.w * w_s.w;
    float rd = val.x * w_d.x + val.y * w_d.y + val.z * w_d.z + val.w * w_d.w;
    rs += __shfl_xor(rs, 1); rs += __shfl_xor(rs, 2);
    rd += __shfl_xor(rd, 1); rd += __shfl_xor(rd, 2);
    if (lane == 0) { as2[node] = rs; ad2[node] = rd; }
  } else {
    float4 val;
    val.x = acc.x * inv_s;
    val.y = acc.y * inv_s;
    val.z = acc.z * inv_s;
    val.w = acc.w * inv_s;
    if (lane < 4) ((float4*)(outv + (size_t)node * HID))[lane] = val;
  }
}

// ---------- final: out = log_softmax(agg2 @ W2 + b2), thread-per-node ----------
__global__ __launch_bounds__(256) void k_out(const float* __restrict__ agg2,
                                             const float* __restrict__ W2,
                                             const float* __restrict__ b2,
                                             float* __restrict__ out) {
  int row = blockIdx.x * 256 + threadIdx.x;
  if (row >= N_NODES) return;
  float hv[HID];
  const float4* hp = (const float4*)(agg2 + (size_t)row * HID);
#pragma unroll
  for (int j = 0; j < 4; ++j) {
    float4 v = hp[j];
    hv[4 * j] = v.x; hv[4 * j + 1] = v.y; hv[4 * j + 2] = v.z; hv[4 * j + 3] = v.w;
  }
  float acc[NCLS];
#pragma unroll
  for (int c = 0; c < NCLS; ++c) acc[c] = b2[c];
#pragma unroll
  for (int k = 0; k < HID; ++k) {
    float xv = hv[k];
    const float* Wr = W2 + k * NCLS;
#pragma unroll
    for (int c = 0; c < NCLS; ++c) acc[c] += xv * Wr[c];
  }
  float mx = -1e30f;
#pragma unroll
  for (int c = 0; c < NCLS; ++c) mx = fmaxf(mx, acc[c]);
  float se = 0.f;
#pragma unroll
  for (int c = 0; c < NCLS; ++c) se += __expf(acc[c] - mx);
  float lse = mx + __logf(se);
  float4* op = (float4*)(out + (size_t)row * NCLS);
#pragma unroll
  for (int j = 0; j < 8; ++j)
    op[j] = make_float4(acc[4 * j] - lse, acc[4 * j + 1] - lse,
                        acc[4 * j + 2] - lse, acc[4 * j + 3] - lse);
}

extern "C" void kernel_launch(void* const* d_in, const int* in_sizes, int n_in,
                              void* d_out, int out_size, void* d_ws, size_t ws_size,
                              hipStream_t stream) {
  const float* x    = (const float*)d_in[0];
  const int*   ei   = (const int*)d_in[1];
  const float* W1   = (const float*)d_in[2];
  const float* as1w = (const float*)d_in[3];
  const float* ad1w = (const float*)d_in[4];
  const float* b1   = (const float*)d_in[5];
  const float* W2   = (const float*)d_in[6];
  const float* as2w = (const float*)d_in[7];
  const float* ad2w = (const float*)d_in[8];
  const float* b2   = (const float*)d_in[9];
  float* out = (float*)d_out;

  char* w = (char*)d_ws;
  size_t off = 0;
  auto alloc = [&](size_t bytes) -> char* {
    char* p = w + off;
    off += (bytes + 511) & ~(size_t)511;
    return p;
  };
  int*   flag  = (int*)alloc(4);
  int*   tot   = (int*)alloc((size_t)NBKT * 4);
  int*   bbase = (int*)alloc((size_t)NBKT * 4);
  int*   cbase = (int*)alloc((size_t)NBKT * 4);
  int*   offs  = (int*)alloc((size_t)(N_NODES + 1) * 4);
  int*   srcS  = (int*)alloc((size_t)N_TOT * 4);
  float* ws2   = (float*)alloc((size_t)HID * 4);
  float* wd2   = (float*)alloc((size_t)HID * 4);

  // union region: {binned 12.8MB + H 1.6MB} (CSR build) vs layer arrays.
  // binned/H are dead before k_gemm1 writes h1 (stream-ordered).
  size_t region_begin = off;
  int* binned = (int*)alloc((size_t)N_EDGES * 4);
  int* H      = (int*)alloc((size_t)G_GROUPS * NBKT * 4);
  off = region_begin;
  float* h1   = (float*)alloc((size_t)N_NODES * HID * 4);
  float* as1  = (float*)alloc((size_t)N_NODES * 4);
  float* ad1  = (float*)alloc((size_t)N_NODES * 4);
  float* hr   = (float*)alloc((size_t)N_NODES * HID * 4);
  float* agg2 = (float*)alloc((size_t)N_NODES * HID * 4);
  float* as2  = (float*)alloc((size_t)N_NODES * 4);
  float* ad2  = (float*)alloc((size_t)N_NODES * 4);

  k_detect<<<1, 64, 0, stream>>>(ei, flag);
  k_hist<<<G_GROUPS, 256, 0, stream>>>(ei, flag, H);
  k_colscan<<<NBKT, G_GROUPS, 0, stream>>>(H, tot);
  k_bscan<<<1, 256, 0, stream>>>(tot, bbase, cbase, offs);
  k_scatter<<<G_GROUPS, 256, 0, stream>>>(ei, flag, H, bbase, binned);
  k_bucket<<<NBKT, 256, 0, stream>>>(tot, bbase, cbase, binned, offs, srcS);
  k_gemm1<<<(N_NODES + 63) / 64, 256, 0, stream>>>(x, W1, as1w, ad1w, h1, as1, ad1);
  k_prep<<<1, 64, 0, stream>>>(W2, as2w, ad2w, ws2, wd2);
  k_agg<true><<<(N_NODES + 3) / 4, 256, 0, stream>>>(offs, srcS, as1, ad1, h1,
                                                     b1, ws2, wd2, hr, as2, ad2);
  k_agg<false><<<(N_NODES + 3) / 4, 256, 0, stream>>>(offs, srcS, as2, ad2, hr,
                                                      nullptr, nullptr, nullptr,
                                                      agg2, nullptr, nullptr);
  k_out<<<(N_NODES + 255) / 256, 256, 0, stream>>>(agg2, W2, b2, out);
}